// Round 12
// baseline (3361.512 us; speedup 1.0000x reference)
//
#include <hip/hip_runtime.h>
#include <math.h>

#define BS 32
#define M 64
#define NMAT 2048      // BS*M
#define DIN 100
#define DOUT 64
#define DD 4096        // DOUT*DOUT
#define EPSV 1e-6f
#define NSWEEP_1S 7

__device__ __forceinline__ float bperm(int addr, float v) {
    return __int_as_float(__builtin_amdgcn_ds_bpermute(addr, __float_as_int(v)));
}

// ---------------- transform: S = W^T X W for each of q,k,v ----------------
__global__ __launch_bounds__(256) void transform_kernel(
    const float* __restrict__ x,
    const float* __restrict__ Wq, const float* __restrict__ Wk, const float* __restrict__ Wv,
    float* __restrict__ Qo, float* __restrict__ Ko, float* __restrict__ Vo)
{
    __shared__ float Xs[DIN][DIN + 1];      // 100x101
    __shared__ float Ws[DIN][DOUT + 1];     // 100x65
    __shared__ float Ts[DIN][DOUT + 1];     // 100x65
    const int n = blockIdx.x;
    const int t = threadIdx.x;
    const float* Xp = x + (size_t)n * DIN * DIN;
    for (int idx = t; idx < DIN * DIN; idx += 256)
        Xs[idx / DIN][idx % DIN] = Xp[idx];

    const float* Wlist[3] = {Wq, Wk, Wv};
    float* Olist[3] = {Qo, Ko, Vo};
    const int tj = t & 63;   // 0..63
    const int tp = t >> 6;   // 0..3

    for (int w = 0; w < 3; ++w) {
        __syncthreads();     // Xs ready (w=0); Ws/Ts free (w>0)
        const float* W = Wlist[w];
        for (int idx = t; idx < DIN * DOUT; idx += 256)
            Ws[idx / DOUT][idx % DOUT] = W[idx];
        __syncthreads();
        // T = X * W : thread computes T[p][tj] for p = tp + 4*pi
        float acc[25];
        #pragma unroll
        for (int i = 0; i < 25; ++i) acc[i] = 0.f;
        for (int qq = 0; qq < DIN; ++qq) {
            float wv = Ws[qq][tj];
            #pragma unroll
            for (int pi = 0; pi < 25; ++pi)
                acc[pi] += Xs[tp + 4 * pi][qq] * wv;
        }
        #pragma unroll
        for (int pi = 0; pi < 25; ++pi)
            Ts[tp + 4 * pi][tj] = acc[pi];
        __syncthreads();
        // S = W^T * T : thread computes S[i][tj] for i = tp + 4*ii
        float sacc[16];
        #pragma unroll
        for (int i = 0; i < 16; ++i) sacc[i] = 0.f;
        for (int p = 0; p < DIN; ++p) {
            float tv = Ts[p][tj];
            #pragma unroll
            for (int ii = 0; ii < 16; ++ii)
                sacc[ii] += Ws[p][tp + 4 * ii] * tv;
        }
        float* Op = Olist[w] + (size_t)n * DD;
        #pragma unroll
        for (int ii = 0; ii < 16; ++ii)
            Op[(tp + 4 * ii) * DOUT + tj] = sacc[ii];
    }
}

// ---------------- one-sided Jacobi (SVD) — TWO waves per matrix -----------
// R11 postmortem: one wave holding g[64]+gp[64] overflows arch VGPRs ->
// AGPR staging (+230 VALU inst/round) AND DS remat (2x bpermute). Split the
// matrix across 2 waves: wave wid holds rows [wid*32, wid*32+32) of all 64
// columns (g[32] per lane). Partner-column fetch = 32 bperms, once, in arch
// VGPRs. Per-round cross-wave dot combine via LDS (parity double-buffer) +
// one barrier. Block = 128 threads = 1 matrix.
__global__ __launch_bounds__(128, 4) void jacobi1s_kernel(
    float* __restrict__ Q, float* __restrict__ K, float* __restrict__ V,
    float* __restrict__ wbuf, float* __restrict__ qn, float* __restrict__ kn)
{
    __shared__ float part[2][2][64];   // [parity][wave][lane]
    const int lane = threadIdx.x & 63;
    const int wid  = threadIdx.x >> 6;   // 0 or 1
    const int mat  = blockIdx.x;
    float* base;
    float* nrm = nullptr;
    if (mat < NMAT)          { base = Q + (size_t)mat * DD;            nrm = qn + mat; }
    else if (mat < 2 * NMAT) { base = K + (size_t)(mat - NMAT) * DD;   nrm = kn + (mat - NMAT); }
    else                     { base = V + (size_t)(mat - 2 * NMAT) * DD; }

    // Lane owns column `lane`, rows [wid*32, wid*32+32). A symmetric:
    // column-lane elements = row-lane elements -> contiguous float4 loads.
    float g[32];
    {
        const float4* rp = (const float4*)(base + (size_t)lane * DOUT + wid * 32);
        #pragma unroll
        for (int i = 0; i < 8; ++i) {
            float4 v = rp[i];
            g[4 * i + 0] = v.x; g[4 * i + 1] = v.y;
            g[4 * i + 2] = v.z; g[4 * i + 3] = v.w;
        }
    }

    for (int sw = 0; sw < NSWEEP_1S; ++sw) {
        // full-column norm: combine the two half-norms (exact, per sweep)
        float nself;
        {
            float n0 = 0.f, n1 = 0.f, n2 = 0.f, n3 = 0.f;
            #pragma unroll
            for (int i = 0; i < 32; i += 4) {
                n0 = fmaf(g[i + 0], g[i + 0], n0);
                n1 = fmaf(g[i + 1], g[i + 1], n1);
                n2 = fmaf(g[i + 2], g[i + 2], n2);
                n3 = fmaf(g[i + 3], g[i + 3], n3);
            }
            part[1][wid][lane] = (n0 + n1) + (n2 + n3);
        }
        __syncthreads();
        nself = part[1][0][lane] + part[1][1][lane];   // identical in both waves
        #pragma unroll 1
        for (int rr = 0; rr < 63; ++rr) {
            const int Kx = rr + 1;
            const int partner = lane ^ Kx;
            const int paddr = partner << 2;
            const float dpart = bperm(paddr, nself);

            // fetch partner half-column (once; fits arch VGPRs)
            float gp[32];
            #pragma unroll
            for (int i = 0; i < 32; ++i) gp[i] = bperm(paddr, g[i]);
            // partial dot, 4 chains
            float d0 = 0.f, d1 = 0.f, d2 = 0.f, d3 = 0.f;
            #pragma unroll
            for (int i = 0; i < 32; i += 4) {
                d0 = fmaf(g[i + 0], gp[i + 0], d0);
                d1 = fmaf(g[i + 1], gp[i + 1], d1);
                d2 = fmaf(g[i + 2], gp[i + 2], d2);
                d3 = fmaf(g[i + 3], gp[i + 3], d3);
            }
            part[rr & 1][wid][lane] = (d0 + d1) + (d2 + d3);
            __syncthreads();
            const float dot = part[rr & 1][0][lane] + part[rr & 1][1][lane];

            // rotation params for ordered pair (p,q) = (min,max) — identical
            // in both waves (dot, nself, dpart all identical)
            const bool isp = lane < partner;
            const float dpp = isp ? nself : dpart;
            const float dqq = isp ? dpart : nself;
            float c = 1.f, s = 0.f, tt = 0.f;
            if (dot * dot > 1e-16f * dpp * dqq) {
                float theta = (dqq - dpp) / (2.f * dot);
                tt = 1.f / (fabsf(theta) + sqrtf(1.f + theta * theta));
                if (theta < 0.f) tt = -tt;
                c = rsqrtf(1.f + tt * tt);
                s = tt * c;
            }
            const float sgn = isp ? -s : s;
            #pragma unroll
            for (int i = 0; i < 32; ++i)
                g[i] = fmaf(c, g[i], sgn * gp[i]);
            nself = fmaf(isp ? -tt : tt, dot, nself);
        }
        __syncthreads();   // protect part[] reuse across sweep boundary
    }

    // epilogue: combine half-norms -> sigma, f, w
    {
        float n0 = 0.f, n1 = 0.f, n2 = 0.f, n3 = 0.f;
        #pragma unroll
        for (int i = 0; i < 32; i += 4) {
            n0 = fmaf(g[i + 0], g[i + 0], n0);
            n1 = fmaf(g[i + 1], g[i + 1], n1);
            n2 = fmaf(g[i + 2], g[i + 2], n2);
            n3 = fmaf(g[i + 3], g[i + 3], n3);
        }
        part[0][wid][lane] = (n0 + n1) + (n2 + n3);
    }
    __syncthreads();
    const float d = part[0][0][lane] + part[0][1][lane];
    const float sigma = sqrtf(d);
    const float f = logf(sigma + EPSV);
    const float w = f / d;

    // write back own half: row (wid*32+i), col lane -> coalesced
    #pragma unroll
    for (int i = 0; i < 32; ++i)
        base[(size_t)(wid * 32 + i) * DOUT + lane] = g[i];
    if (wid == 0) {
        wbuf[(size_t)mat * 64 + lane] = w;
        if (nrm != nullptr) {
            float nf = f * f;
            #pragma unroll
            for (int off = 32; off >= 1; off >>= 1) nf += __shfl_xor(nf, off, 64);
            if (lane == 0) *nrm = nf;
        }
    }
}

// ---------------- reconstruction: logA = G diag(w) G^T, in place ----------
__global__ __launch_bounds__(256) void recon_log_kernel(
    float* __restrict__ Q, float* __restrict__ K, float* __restrict__ V,
    const float* __restrict__ wbuf)
{
    __shared__ float Gs[64][65];
    __shared__ float Bs[64][65];
    __shared__ float ws[64];
    const int t = threadIdx.x;
    const int mat = blockIdx.x;
    float* base;
    if (mat < NMAT)          base = Q + (size_t)mat * DD;
    else if (mat < 2 * NMAT) base = K + (size_t)(mat - NMAT) * DD;
    else                     base = V + (size_t)(mat - 2 * NMAT) * DD;

    for (int idx = t; idx < DD; idx += 256)
        Gs[idx >> 6][idx & 63] = base[idx];
    if (t < 64) ws[t] = wbuf[(size_t)mat * 64 + t];
    __syncthreads();
    for (int idx = t; idx < DD; idx += 256) {
        int r = idx >> 6, c = idx & 63;
        Bs[r][c] = Gs[r][c] * ws[c];
    }
    __syncthreads();
    // out[i][j] = sum_k Bs[i][k] * Gs[j][k] ; 4x4 register tile per thread
    const int ti = t >> 4, tj = t & 15;
    float acc[4][4];
    #pragma unroll
    for (int i = 0; i < 4; ++i)
        #pragma unroll
        for (int j = 0; j < 4; ++j) acc[i][j] = 0.f;
    for (int k = 0; k < 64; ++k) {
        float av[4], bv[4];
        #pragma unroll
        for (int d = 0; d < 4; ++d) { av[d] = Bs[4 * ti + d][k]; bv[d] = Gs[4 * tj + d][k]; }
        #pragma unroll
        for (int i = 0; i < 4; ++i)
            #pragma unroll
            for (int j = 0; j < 4; ++j)
                acc[i][j] += av[i] * bv[j];
    }
    #pragma unroll
    for (int i = 0; i < 4; ++i) {
        float4 v;
        v.x = acc[i][0]; v.y = acc[i][1]; v.z = acc[i][2]; v.w = acc[i][3];
        *(float4*)(base + (4 * ti + i) * DOUT + 4 * tj) = v;
    }
}

// ---------------- scores + softmax (per batch) ----------------------------
__global__ __launch_bounds__(256) void scores_kernel(
    const float* __restrict__ logK, const float* __restrict__ logQ,
    const float* __restrict__ kn, const float* __restrict__ qn,
    float* __restrict__ prob)
{
    __shared__ float kf_t[64][65];
    __shared__ float qf_t[64][65];
    __shared__ float sc[64][65];
    __shared__ float mx[64], sm[64];
    const int b = blockIdx.x;
    const int t = threadIdx.x;
    const int ti = t >> 4, tjj = t & 15;
    float acc[4][4];
    #pragma unroll
    for (int di = 0; di < 4; ++di)
        #pragma unroll
        for (int dj = 0; dj < 4; ++dj) acc[di][dj] = 0.f;

    const float* Kb = logK + (size_t)b * M * DD;
    const float* Qb = logQ + (size_t)b * M * DD;
    for (int cf = 0; cf < DD; cf += 64) {
        __syncthreads();
        for (int idx = t; idx < 64 * 64; idx += 256) {
            int r = idx >> 6, c = idx & 63;
            kf_t[r][c] = Kb[(size_t)r * DD + cf + c];
            qf_t[r][c] = Qb[(size_t)r * DD + cf + c];
        }
        __syncthreads();
        for (int f = 0; f < 64; ++f) {
            float kv[4], qv[4];
            #pragma unroll
            for (int d = 0; d < 4; ++d) { kv[d] = kf_t[4 * ti + d][f]; qv[d] = qf_t[4 * tjj + d][f]; }
            #pragma unroll
            for (int di = 0; di < 4; ++di)
                #pragma unroll
                for (int dj = 0; dj < 4; ++dj)
                    acc[di][dj] += kv[di] * qv[dj];
        }
    }
    __syncthreads();
    #pragma unroll
    for (int di = 0; di < 4; ++di) {
        #pragma unroll
        for (int dj = 0; dj < 4; ++dj) {
            int i = 4 * ti + di, j = 4 * tjj + dj;
            float dist = kn[b * 64 + i] + qn[b * 64 + j] - 2.f * acc[di][dj];
            dist = fmaxf(dist, 0.f) + 64.f * EPSV;
            sc[i][j] = 1.f / (1.f + log1pf(dist));
        }
    }
    __syncthreads();
    if (t < 64) {
        int j = t;
        float m = -1e30f;
        for (int i = 0; i < 64; ++i) m = fmaxf(m, sc[i][j]);
        float ssum = 0.f;
        for (int i = 0; i < 64; ++i) ssum += expf(sc[i][j] - m);
        mx[j] = m; sm[j] = ssum;
    }
    __syncthreads();
    float* Pb = prob + (size_t)b * M * M;
    for (int idx = t; idx < 64 * 64; idx += 256) {
        int j = idx >> 6, i = idx & 63;
        Pb[idx] = expf(sc[i][j] - mx[j]) / sm[j];
    }
}

// ---------------- mixed = prob @ vf  (one block per output row) -----------
__global__ __launch_bounds__(256) void mixed_kernel(
    const float* __restrict__ prob, const float* __restrict__ logV,
    float* __restrict__ mixed)
{
    __shared__ float pr[64];
    const int n = blockIdx.x;        // b*64 + j
    const int b = n >> 6, j = n & 63;
    const int t = threadIdx.x;
    if (t < 64) pr[t] = prob[((size_t)b * 64 + j) * 64 + t];
    __syncthreads();
    const float4* Vb = (const float4*)(logV + (size_t)b * M * DD);
    float4 acc[4];
    #pragma unroll
    for (int u = 0; u < 4; ++u) acc[u] = make_float4(0.f, 0.f, 0.f, 0.f);
    for (int i = 0; i < 64; ++i) {
        float p = pr[i];
        const float4* row = Vb + (size_t)i * (DD / 4);
        #pragma unroll
        for (int u = 0; u < 4; ++u) {
            float4 v = row[t + 256 * u];
            acc[u].x += p * v.x; acc[u].y += p * v.y;
            acc[u].z += p * v.z; acc[u].w += p * v.w;
        }
    }
    float4* Mp = (float4*)(mixed + (size_t)n * DD);
    #pragma unroll
    for (int u = 0; u < 4; ++u) Mp[t + 256 * u] = acc[u];
}

// ---------------- exp via scaling-and-squaring Taylor (deg 8) -------------
__device__ __forceinline__ void mm64(const float (*A)[DOUT + 1], const float (*B)[DOUT + 1],
                                     float (*C)[DOUT + 1], int t)
{
    const int ti = t >> 4, tj = t & 15;
    float acc[4][4];
    #pragma unroll
    for (int i = 0; i < 4; ++i)
        #pragma unroll
        for (int j = 0; j < 4; ++j) acc[i][j] = 0.f;
    for (int k = 0; k < 64; ++k) {
        float av[4], bv[4];
        #pragma unroll
        for (int d = 0; d < 4; ++d) { av[d] = A[4 * ti + d][k]; bv[d] = B[k][4 * tj + d]; }
        #pragma unroll
        for (int i = 0; i < 4; ++i)
            #pragma unroll
            for (int j = 0; j < 4; ++j)
                acc[i][j] += av[i] * bv[j];
    }
    #pragma unroll
    for (int i = 0; i < 4; ++i)
        #pragma unroll
        for (int j = 0; j < 4; ++j)
            C[4 * ti + i][4 * tj + j] = acc[i][j];
}

__global__ __launch_bounds__(256) void exp_ss_kernel(
    const float* __restrict__ in, float* __restrict__ out)
{
    __shared__ float Bs[DOUT][DOUT + 1];
    __shared__ float Ps[DOUT][DOUT + 1];
    __shared__ float Ts[DOUT][DOUT + 1];
    __shared__ float red[64];
    __shared__ int s_sh;
    __shared__ float scl_sh;
    const int t = threadIdx.x;
    const float* Ap = in + (size_t)blockIdx.x * DD;
    float* Gp = out + (size_t)blockIdx.x * DD;

    for (int idx = t; idx < DD; idx += 256) {
        Bs[idx >> 6][idx & 63] = Ap[idx];
    }
    __syncthreads();
    if (t < 64) {
        float s = 0.f;
        for (int c = 0; c < 64; ++c) s += fabsf(Bs[t][c]);
        red[t] = s;
    }
    __syncthreads();
    if (t == 0) {
        float mx = 0.f;
        for (int k = 0; k < 64; ++k) mx = fmaxf(mx, red[k]);
        int s = 0;
        while (mx > 0.7f && s < 30) { mx *= 0.5f; ++s; }
        s_sh = s;
        scl_sh = ldexpf(1.f, -s);
    }
    __syncthreads();
    const int nsq = s_sh;
    const float scl = scl_sh;
    // scale B in place; init P = I + B/8  (degree-8 Taylor, ||B||1 <= 0.7)
    for (int idx = t; idx < DD; idx += 256) {
        int r = idx >> 6, c = idx & 63;
        float b = Bs[r][c] * scl;
        Bs[r][c] = b;
        Ps[r][c] = b * 0.125f + ((r == c) ? 1.f : 0.f);
    }
    __syncthreads();
    // Horner: P <- I + (B*P)/k for k = 7..1
    #pragma unroll 1
    for (int k = 7; k >= 1; --k) {
        mm64(Bs, Ps, Ts, t);
        __syncthreads();
        float rk = 1.f / (float)k;
        for (int idx = t; idx < DD; idx += 256) {
            int r = idx >> 6, c = idx & 63;
            Ps[r][c] = Ts[r][c] * rk + ((r == c) ? 1.f : 0.f);
        }
        __syncthreads();
    }
    // squarings
    #pragma unroll 1
    for (int j = 0; j < nsq; ++j) {
        mm64(Ps, Ps, Ts, t);
        __syncthreads();
        for (int idx = t; idx < DD; idx += 256)
            Ps[idx >> 6][idx & 63] = Ts[idx >> 6][idx & 63];
        __syncthreads();
    }
    for (int idx = t; idx < DD; idx += 256)
        Gp[idx] = Ps[idx >> 6][idx & 63];
}

extern "C" void kernel_launch(void* const* d_in, const int* in_sizes, int n_in,
                              void* d_out, int out_size, void* d_ws, size_t ws_size,
                              hipStream_t stream) {
    const float* x  = (const float*)d_in[0];
    const float* Wq = (const float*)d_in[1];
    const float* Wk = (const float*)d_in[2];
    const float* Wv = (const float*)d_in[3];
    float* out = (float*)d_out;
    float* ws  = (float*)d_ws;

    // ws layout (floats): Q | K | qn | kn | prob | wbuf ; V/logV in d_out.
    float* Q    = ws;
    float* K    = Q + (size_t)NMAT * DD;
    float* qn   = K + (size_t)NMAT * DD;
    float* kn   = qn + NMAT;
    float* prob = kn + NMAT;
    float* wbuf = prob + (size_t)BS * M * M;
    float* V    = out;        // logV staged in d_out
    float* mixed = Q;         // overwrites logQ after scores

    transform_kernel<<<NMAT, 256, 0, stream>>>(x, Wq, Wk, Wv, Q, K, V);
    jacobi1s_kernel<<<3 * NMAT, 128, 0, stream>>>(Q, K, V, wbuf, qn, kn);
    recon_log_kernel<<<3 * NMAT, 256, 0, stream>>>(Q, K, V, wbuf);
    scores_kernel<<<BS, 256, 0, stream>>>(K, Q, kn, qn, prob);
    mixed_kernel<<<NMAT, 256, 0, stream>>>(prob, V, mixed);
    exp_ss_kernel<<<NMAT, 256, 0, stream>>>(mixed, out);
}

// Round 13
// 2574.266 us; speedup vs baseline: 1.3058x; 1.3058x over previous
//
#include <hip/hip_runtime.h>
#include <math.h>

#define BS 32
#define M 64
#define NMAT 2048      // BS*M
#define DIN 100
#define DOUT 64
#define DD 4096        // DOUT*DOUT
#define EPSV 1e-6f
#define NSWEEP_1S 6
#define DS_SPLIT 44    // elements [0,DS_SPLIT) via ds_bpermute, rest via VALU
#define LSTR 68        // LDS row stride for matmul tiles: 16B-aligned, <=2-way bank alias

typedef unsigned int uint2v __attribute__((ext_vector_type(2)));

__device__ __forceinline__ float bperm(int addr, float v) {
    return __int_as_float(__builtin_amdgcn_ds_bpermute(addr, __float_as_int(v)));
}

// DPP lane permute (VALU pipe): 0xB1=lane^1, 0x4E=lane^2, 0x1B=lane^3,
// 0x141=lane^7 (row_half_mirror), 0x140=lane^15 (row_mirror).
template <int CTRL>
__device__ __forceinline__ float dppf(float x) {
    return __int_as_float(__builtin_amdgcn_mov_dpp(__float_as_int(x), CTRL, 0xF, 0xF, true));
}

// Full lane^32 of TWO independent values in 2 instructions (no cndmask):
// swap(a,b): a'=[a_lo,b_lo], b'=[a_hi,b_hi]  (validated R8/R9)
__device__ __forceinline__ void swap32_pair(float& x, float& y) {
#if __has_builtin(__builtin_amdgcn_permlane32_swap)
    uint2v r1 = __builtin_amdgcn_permlane32_swap(__float_as_uint(x), __float_as_uint(y), false, false);
    uint2v r2 = __builtin_amdgcn_permlane32_swap(r1[1], r1[0], false, false);
    x = __uint_as_float(r2[0]);
    y = __uint_as_float(r2[1]);
#else
    int a = ((threadIdx.x & 63) ^ 32) << 2;
    x = bperm(a, x); y = bperm(a, y);
#endif
}
__device__ __forceinline__ void swap16_pair(float& x, float& y) {
#if __has_builtin(__builtin_amdgcn_permlane16_swap)
    uint2v r1 = __builtin_amdgcn_permlane16_swap(__float_as_uint(x), __float_as_uint(y), false, false);
    uint2v r2 = __builtin_amdgcn_permlane16_swap(r1[1], r1[0], false, false);
    x = __uint_as_float(r2[0]);
    y = __uint_as_float(r2[1]);
#else
    int a = ((threadIdx.x & 63) ^ 16) << 2;
    x = bperm(a, x); y = bperm(a, y);
#endif
}

// ---------------- transform: S = W^T X W for each of q,k,v ----------------
__global__ __launch_bounds__(256) void transform_kernel(
    const float* __restrict__ x,
    const float* __restrict__ Wq, const float* __restrict__ Wk, const float* __restrict__ Wv,
    float* __restrict__ Qo, float* __restrict__ Ko, float* __restrict__ Vo)
{
    __shared__ float Xs[DIN][DIN + 1];      // 100x101
    __shared__ float Ws[DIN][DOUT + 1];     // 100x65
    __shared__ float Ts[DIN][DOUT + 1];     // 100x65
    const int n = blockIdx.x;
    const int t = threadIdx.x;
    const float* Xp = x + (size_t)n * DIN * DIN;
    for (int idx = t; idx < DIN * DIN; idx += 256)
        Xs[idx / DIN][idx % DIN] = Xp[idx];

    const float* Wlist[3] = {Wq, Wk, Wv};
    float* Olist[3] = {Qo, Ko, Vo};
    const int tj = t & 63;   // 0..63
    const int tp = t >> 6;   // 0..3

    for (int w = 0; w < 3; ++w) {
        __syncthreads();     // Xs ready (w=0); Ws/Ts free (w>0)
        const float* W = Wlist[w];
        for (int idx = t; idx < DIN * DOUT; idx += 256)
            Ws[idx / DOUT][idx % DOUT] = W[idx];
        __syncthreads();
        // T = X * W : thread computes T[p][tj] for p = tp + 4*pi
        float acc[25];
        #pragma unroll
        for (int i = 0; i < 25; ++i) acc[i] = 0.f;
        for (int qq = 0; qq < DIN; ++qq) {
            float wv = Ws[qq][tj];
            #pragma unroll
            for (int pi = 0; pi < 25; ++pi)
                acc[pi] += Xs[tp + 4 * pi][qq] * wv;
        }
        #pragma unroll
        for (int pi = 0; pi < 25; ++pi)
            Ts[tp + 4 * pi][tj] = acc[pi];
        __syncthreads();
        // S = W^T * T : thread computes S[i][tj] for i = tp + 4*ii
        float sacc[16];
        #pragma unroll
        for (int i = 0; i < 16; ++i) sacc[i] = 0.f;
        for (int p = 0; p < DIN; ++p) {
            float tv = Ts[p][tj];
            #pragma unroll
            for (int ii = 0; ii < 16; ++ii)
                sacc[ii] += Ws[p][tp + 4 * ii] * tv;
        }
        float* Op = Olist[w] + (size_t)n * DD;
        #pragma unroll
        for (int ii = 0; ii < 16; ++ii)
            Op[(tp + 4 * ii) * DOUT + tj] = sacc[ii];
    }
}

// ---------------- one-sided Jacobi (SVD) — one wave per matrix ------------
// R10 structure (best measured: 1782us): two-pipe exchange, elements
// [0,44) DS (bpermute), [44,64) VALU (DPP + permlane pair-swaps). 6 sweeps
// (R13: error curve 8sw->0.0039, 7sw->0.0078 => 6sw ~0.0156 < 0.0211 thr).
__global__ __launch_bounds__(256, 3) void jacobi1s_kernel(
    float* __restrict__ Q, float* __restrict__ K, float* __restrict__ V,
    float* __restrict__ wbuf, float* __restrict__ qn, float* __restrict__ kn)
{
    const int lane = threadIdx.x & 63;
    const int wid  = threadIdx.x >> 6;
    const int mat  = blockIdx.x * 4 + wid;
    float* base;
    float* nrm = nullptr;
    if (mat < NMAT)          { base = Q + (size_t)mat * DD;            nrm = qn + mat; }
    else if (mat < 2 * NMAT) { base = K + (size_t)(mat - NMAT) * DD;   nrm = kn + (mat - NMAT); }
    else                     { base = V + (size_t)(mat - 2 * NMAT) * DD; }

    // Lane `lane` owns column `lane`. A is symmetric -> column == row.
    float g[64];
    {
        const float4* rp = (const float4*)(base + (size_t)lane * DOUT);
        #pragma unroll
        for (int i = 0; i < 16; ++i) {
            float4 v = rp[i];
            g[4 * i + 0] = v.x; g[4 * i + 1] = v.y;
            g[4 * i + 2] = v.z; g[4 * i + 3] = v.w;
        }
    }

    for (int sw = 0; sw < NSWEEP_1S; ++sw) {
        // exact norm at sweep start (kills incremental drift)
        float nself;
        {
            float n0 = 0.f, n1 = 0.f, n2 = 0.f, n3 = 0.f;
            #pragma unroll
            for (int i = 0; i < 64; i += 4) {
                n0 = fmaf(g[i + 0], g[i + 0], n0);
                n1 = fmaf(g[i + 1], g[i + 1], n1);
                n2 = fmaf(g[i + 2], g[i + 2], n2);
                n3 = fmaf(g[i + 3], g[i + 3], n3);
            }
            nself = (n0 + n1) + (n2 + n3);
        }
        #pragma unroll 1
        for (int rr = 0; rr < 63; ++rr) {
            const int Kx = rr + 1;
            const int partner = lane ^ Kx;
            const int paddr = partner << 2;
            const float dpart = bperm(paddr, nself);

            float gp[64];
            // ---- DS portion: elements [0,DS_SPLIT) via bpermute ----
            #pragma unroll
            for (int i = 0; i < DS_SPLIT; ++i) gp[i] = bperm(paddr, g[i]);
            // ---- VALU portion: elements [DS_SPLIT,64) via DPP/permlane ----
            #pragma unroll
            for (int i = DS_SPLIT; i < 64; ++i) gp[i] = g[i];
            if (Kx & 32) {
                #pragma unroll
                for (int i = DS_SPLIT; i < 64; i += 2) swap32_pair(gp[i], gp[i + 1]);
            }
            if (Kx & 16) {
                #pragma unroll
                for (int i = DS_SPLIT; i < 64; i += 2) swap16_pair(gp[i], gp[i + 1]);
            }
            {
                const int low4 = Kx & 15;
                const bool m_f = (low4 & 8) != 0;
                const int n4 = m_f ? (low4 ^ 15) : low4;
                const bool h_f = (n4 & 4) != 0;
                const int q = h_f ? (n4 ^ 7) : n4;   // 0..3
                if (m_f) {
                    #pragma unroll
                    for (int i = DS_SPLIT; i < 64; ++i) gp[i] = dppf<0x140>(gp[i]);
                }
                if (h_f) {
                    #pragma unroll
                    for (int i = DS_SPLIT; i < 64; ++i) gp[i] = dppf<0x141>(gp[i]);
                }
                if (q == 1) {
                    #pragma unroll
                    for (int i = DS_SPLIT; i < 64; ++i) gp[i] = dppf<0xB1>(gp[i]);
                } else if (q == 2) {
                    #pragma unroll
                    for (int i = DS_SPLIT; i < 64; ++i) gp[i] = dppf<0x4E>(gp[i]);
                } else if (q == 3) {
                    #pragma unroll
                    for (int i = DS_SPLIT; i < 64; ++i) gp[i] = dppf<0x1B>(gp[i]);
                }
            }

            // dot via 4 split chains
            float d0 = 0.f, d1 = 0.f, d2 = 0.f, d3 = 0.f;
            #pragma unroll
            for (int i = 0; i < 64; i += 4) {
                d0 = fmaf(g[i + 0], gp[i + 0], d0);
                d1 = fmaf(g[i + 1], gp[i + 1], d1);
                d2 = fmaf(g[i + 2], gp[i + 2], d2);
                d3 = fmaf(g[i + 3], gp[i + 3], d3);
            }
            const float dot = (d0 + d1) + (d2 + d3);

            // rotation params for ordered pair (p,q) = (min,max)
            const bool isp = lane < partner;
            const float dpp = isp ? nself : dpart;
            const float dqq = isp ? dpart : nself;
            float c = 1.f, s = 0.f, tt = 0.f;
            if (dot * dot > 1e-16f * dpp * dqq) {
                float theta = (dqq - dpp) / (2.f * dot);
                tt = 1.f / (fabsf(theta) + sqrtf(1.f + theta * theta));
                if (theta < 0.f) tt = -tt;
                c = rsqrtf(1.f + tt * tt);
                s = tt * c;
            }
            const float sgn = isp ? -s : s;
            #pragma unroll
            for (int i = 0; i < 64; ++i)
                g[i] = fmaf(c, g[i], sgn * gp[i]);
            nself = fmaf(isp ? -tt : tt, dot, nself);
        }
    }

    // epilogue: sigma, f = log(sigma+eps), w = f/sigma^2
    float d;
    {
        float n0 = 0.f, n1 = 0.f, n2 = 0.f, n3 = 0.f;
        #pragma unroll
        for (int i = 0; i < 64; i += 4) {
            n0 = fmaf(g[i + 0], g[i + 0], n0);
            n1 = fmaf(g[i + 1], g[i + 1], n1);
            n2 = fmaf(g[i + 2], g[i + 2], n2);
            n3 = fmaf(g[i + 3], g[i + 3], n3);
        }
        d = (n0 + n1) + (n2 + n3);
    }
    float sigma = sqrtf(d);
    float f = logf(sigma + EPSV);
    float w = f / d;

    // write G back (lane's column scattered across rows -> coalesced stores)
    #pragma unroll
    for (int i = 0; i < 64; ++i) base[i * DOUT + lane] = g[i];
    wbuf[(size_t)mat * 64 + lane] = w;

    if (nrm != nullptr) {
        float nf = f * f;
        #pragma unroll
        for (int off = 32; off >= 1; off >>= 1) nf += __shfl_xor(nf, off, 64);
        if (lane == 0) *nrm = nf;
    }
}

// ---------------- reconstruction: logA = G diag(w) G^T, in place ----------
// float4 LDS reads in k-chunks of 4 (stride LSTR=68: 16B-aligned rows,
// <=2-way bank alias). Same fma order as scalar version -> bit-identical.
__global__ __launch_bounds__(256) void recon_log_kernel(
    float* __restrict__ Q, float* __restrict__ K, float* __restrict__ V,
    const float* __restrict__ wbuf)
{
    __shared__ float Gs[64][LSTR];
    __shared__ float Bs[64][LSTR];
    __shared__ float ws[64];
    const int t = threadIdx.x;
    const int mat = blockIdx.x;
    float* base;
    if (mat < NMAT)          base = Q + (size_t)mat * DD;
    else if (mat < 2 * NMAT) base = K + (size_t)(mat - NMAT) * DD;
    else                     base = V + (size_t)(mat - 2 * NMAT) * DD;

    for (int idx = t; idx < DD; idx += 256)
        Gs[idx >> 6][idx & 63] = base[idx];
    if (t < 64) ws[t] = wbuf[(size_t)mat * 64 + t];
    __syncthreads();
    for (int idx = t; idx < DD; idx += 256) {
        int r = idx >> 6, c = idx & 63;
        Bs[r][c] = Gs[r][c] * ws[c];
    }
    __syncthreads();
    // out[i][j] = sum_k Bs[i][k] * Gs[j][k] ; 4x4 register tile per thread
    const int ti = t >> 4, tj = t & 15;
    float acc[4][4];
    #pragma unroll
    for (int i = 0; i < 4; ++i)
        #pragma unroll
        for (int j = 0; j < 4; ++j) acc[i][j] = 0.f;
    for (int k4 = 0; k4 < 64; k4 += 4) {
        float4 a[4], b[4];
        #pragma unroll
        for (int d = 0; d < 4; ++d) a[d] = *(const float4*)&Bs[4 * ti + d][k4];
        #pragma unroll
        for (int d = 0; d < 4; ++d) b[d] = *(const float4*)&Gs[4 * tj + d][k4];
        #pragma unroll
        for (int kk = 0; kk < 4; ++kk) {
            #pragma unroll
            for (int i = 0; i < 4; ++i) {
                float av = ((const float*)&a[i])[kk];
                #pragma unroll
                for (int j = 0; j < 4; ++j)
                    acc[i][j] += av * ((const float*)&b[j])[kk];
            }
        }
    }
    #pragma unroll
    for (int i = 0; i < 4; ++i) {
        float4 v;
        v.x = acc[i][0]; v.y = acc[i][1]; v.z = acc[i][2]; v.w = acc[i][3];
        *(float4*)(base + (4 * ti + i) * DOUT + 4 * tj) = v;
    }
}

// ---------------- scores + softmax (per batch) ----------------------------
__global__ __launch_bounds__(256) void scores_kernel(
    const float* __restrict__ logK, const float* __restrict__ logQ,
    const float* __restrict__ kn, const float* __restrict__ qn,
    float* __restrict__ prob)
{
    __shared__ float kf_t[64][65];
    __shared__ float qf_t[64][65];
    __shared__ float sc[64][65];
    __shared__ float mx[64], sm[64];
    const int b = blockIdx.x;
    const int t = threadIdx.x;
    const int ti = t >> 4, tjj = t & 15;
    float acc[4][4];
    #pragma unroll
    for (int di = 0; di < 4; ++di)
        #pragma unroll
        for (int dj = 0; dj < 4; ++dj) acc[di][dj] = 0.f;

    const float* Kb = logK + (size_t)b * M * DD;
    const float* Qb = logQ + (size_t)b * M * DD;
    for (int cf = 0; cf < DD; cf += 64) {
        __syncthreads();
        for (int idx = t; idx < 64 * 64; idx += 256) {
            int r = idx >> 6, c = idx & 63;
            kf_t[r][c] = Kb[(size_t)r * DD + cf + c];
            qf_t[r][c] = Qb[(size_t)r * DD + cf + c];
        }
        __syncthreads();
        for (int f = 0; f < 64; ++f) {
            float kv[4], qv[4];
            #pragma unroll
            for (int d = 0; d < 4; ++d) { kv[d] = kf_t[4 * ti + d][f]; qv[d] = qf_t[4 * tjj + d][f]; }
            #pragma unroll
            for (int di = 0; di < 4; ++di)
                #pragma unroll
                for (int dj = 0; dj < 4; ++dj)
                    acc[di][dj] += kv[di] * qv[dj];
        }
    }
    __syncthreads();
    #pragma unroll
    for (int di = 0; di < 4; ++di) {
        #pragma unroll
        for (int dj = 0; dj < 4; ++dj) {
            int i = 4 * ti + di, j = 4 * tjj + dj;
            float dist = kn[b * 64 + i] + qn[b * 64 + j] - 2.f * acc[di][dj];
            dist = fmaxf(dist, 0.f) + 64.f * EPSV;
            sc[i][j] = 1.f / (1.f + log1pf(dist));
        }
    }
    __syncthreads();
    if (t < 64) {
        int j = t;
        float m = -1e30f;
        for (int i = 0; i < 64; ++i) m = fmaxf(m, sc[i][j]);
        float ssum = 0.f;
        for (int i = 0; i < 64; ++i) ssum += expf(sc[i][j] - m);
        mx[j] = m; sm[j] = ssum;
    }
    __syncthreads();
    float* Pb = prob + (size_t)b * M * M;
    for (int idx = t; idx < 64 * 64; idx += 256) {
        int j = idx >> 6, i = idx & 63;
        Pb[idx] = expf(sc[i][j] - mx[j]) / sm[j];
    }
}

// ---------------- mixed = prob @ vf  (one block per output row) -----------
__global__ __launch_bounds__(256) void mixed_kernel(
    const float* __restrict__ prob, const float* __restrict__ logV,
    float* __restrict__ mixed)
{
    __shared__ float pr[64];
    const int n = blockIdx.x;        // b*64 + j
    const int b = n >> 6, j = n & 63;
    const int t = threadIdx.x;
    if (t < 64) pr[t] = prob[((size_t)b * 64 + j) * 64 + t];
    __syncthreads();
    const float4* Vb = (const float4*)(logV + (size_t)b * M * DD);
    float4 acc[4];
    #pragma unroll
    for (int u = 0; u < 4; ++u) acc[u] = make_float4(0.f, 0.f, 0.f, 0.f);
    for (int i = 0; i < 64; ++i) {
        float p = pr[i];
        const float4* row = Vb + (size_t)i * (DD / 4);
        #pragma unroll
        for (int u = 0; u < 4; ++u) {
            float4 v = row[t + 256 * u];
            acc[u].x += p * v.x; acc[u].y += p * v.y;
            acc[u].z += p * v.z; acc[u].w += p * v.w;
        }
    }
    float4* Mp = (float4*)(mixed + (size_t)n * DD);
    #pragma unroll
    for (int u = 0; u < 4; ++u) Mp[t + 256 * u] = acc[u];
}

// ---------------- exp via scaling-and-squaring Taylor (deg 8) -------------
// mm64: A-side float4 over k (chunks of 4), B-side float4 over j.
// Same k order and fma order as scalar version -> bit-identical.
__device__ __forceinline__ void mm64(const float (*A)[LSTR], const float (*B)[LSTR],
                                     float (*C)[LSTR], int t)
{
    const int ti = t >> 4, tj = t & 15;
    float acc[4][4];
    #pragma unroll
    for (int i = 0; i < 4; ++i)
        #pragma unroll
        for (int j = 0; j < 4; ++j) acc[i][j] = 0.f;
    for (int k4 = 0; k4 < 64; k4 += 4) {
        float4 a[4];
        #pragma unroll
        for (int d = 0; d < 4; ++d) a[d] = *(const float4*)&A[4 * ti + d][k4];
        #pragma unroll
        for (int kk = 0; kk < 4; ++kk) {
            float4 bv = *(const float4*)&B[k4 + kk][4 * tj];
            #pragma unroll
            for (int i = 0; i < 4; ++i) {
                float av = ((const float*)&a[i])[kk];
                acc[i][0] += av * bv.x;
                acc[i][1] += av * bv.y;
                acc[i][2] += av * bv.z;
                acc[i][3] += av * bv.w;
            }
        }
    }
    #pragma unroll
    for (int i = 0; i < 4; ++i)
        #pragma unroll
        for (int j = 0; j < 4; ++j)
            C[4 * ti + i][4 * tj + j] = acc[i][j];
}

__global__ __launch_bounds__(256) void exp_ss_kernel(
    const float* __restrict__ in, float* __restrict__ out)
{
    __shared__ float Bs[64][LSTR];
    __shared__ float Ps[64][LSTR];
    __shared__ float Ts[64][LSTR];
    __shared__ float red[64];
    __shared__ int s_sh;
    __shared__ float scl_sh;
    const int t = threadIdx.x;
    const float* Ap = in + (size_t)blockIdx.x * DD;
    float* Gp = out + (size_t)blockIdx.x * DD;

    for (int idx = t; idx < DD; idx += 256) {
        Bs[idx >> 6][idx & 63] = Ap[idx];
    }
    __syncthreads();
    if (t < 64) {
        float s = 0.f;
        for (int c = 0; c < 64; ++c) s += fabsf(Bs[t][c]);
        red[t] = s;
    }
    __syncthreads();
    if (t == 0) {
        float mx = 0.f;
        for (int k = 0; k < 64; ++k) mx = fmaxf(mx, red[k]);
        int s = 0;
        while (mx > 0.7f && s < 30) { mx *= 0.5f; ++s; }
        s_sh = s;
        scl_sh = ldexpf(1.f, -s);
    }
    __syncthreads();
    const int nsq = s_sh;
    const float scl = scl_sh;
    // scale B in place; init P = I + B/8  (degree-8 Taylor, ||B||1 <= 0.7)
    for (int idx = t; idx < DD; idx += 256) {
        int r = idx >> 6, c = idx & 63;
        float b = Bs[r][c] * scl;
        Bs[r][c] = b;
        Ps[r][c] = b * 0.125f + ((r == c) ? 1.f : 0.f);
    }
    __syncthreads();
    // Horner: P <- I + (B*P)/k for k = 7..1
    #pragma unroll 1
    for (int k = 7; k >= 1; --k) {
        mm64(Bs, Ps, Ts, t);
        __syncthreads();
        float rk = 1.f / (float)k;
        for (int idx = t; idx < DD; idx += 256) {
            int r = idx >> 6, c = idx & 63;
            Ps[r][c] = Ts[r][c] * rk + ((r == c) ? 1.f : 0.f);
        }
        __syncthreads();
    }
    // squarings
    #pragma unroll 1
    for (int j = 0; j < nsq; ++j) {
        mm64(Ps, Ps, Ts, t);
        __syncthreads();
        for (int idx = t; idx < DD; idx += 256)
            Ps[idx >> 6][idx & 63] = Ts[idx >> 6][idx & 63];
        __syncthreads();
    }
    for (int idx = t; idx < DD; idx += 256)
        Gp[idx] = Ps[idx >> 6][idx & 63];
}

extern "C" void kernel_launch(void* const* d_in, const int* in_sizes, int n_in,
                              void* d_out, int out_size, void* d_ws, size_t ws_size,
                              hipStream_t stream) {
    const float* x  = (const float*)d_in[0];
    const float* Wq = (const float*)d_in[1];
    const float* Wk = (const float*)d_in[2];
    const float* Wv = (const float*)d_in[3];
    float* out = (float*)d_out;
    float* ws  = (float*)d_ws;

    // ws layout (floats): Q | K | qn | kn | prob | wbuf ; V/logV in d_out.
    float* Q    = ws;
    float* K    = Q + (size_t)NMAT * DD;
    float* qn   = K + (size_t)NMAT * DD;
    float* kn   = qn + NMAT;
    float* prob = kn + NMAT;
    float* wbuf = prob + (size_t)BS * M * M;
    float* V    = out;        // logV staged in d_out
    float* mixed = Q;         // overwrites logQ after scores

    transform_kernel<<<NMAT, 256, 0, stream>>>(x, Wq, Wk, Wv, Q, K, V);
    jacobi1s_kernel<<<(3 * NMAT) / 4, 256, 0, stream>>>(Q, K, V, wbuf, qn, kn);
    recon_log_kernel<<<3 * NMAT, 256, 0, stream>>>(Q, K, V, wbuf);
    scores_kernel<<<BS, 256, 0, stream>>>(K, Q, kn, qn, prob);
    mixed_kernel<<<NMAT, 256, 0, stream>>>(prob, V, mixed);
    exp_ss_kernel<<<NMAT, 256, 0, stream>>>(mixed, out);
}